// Round 1
// baseline (345.834 us; speedup 1.0000x reference)
//
#include <hip/hip_runtime.h>
#include <hip/hip_bf16.h>

typedef short v8s __attribute__((ext_vector_type(8)));
typedef float f32x4 __attribute__((ext_vector_type(4)));
typedef unsigned short u16;

#define HW_   3136      // 56*56
#define W_    56
#define PW_   58
#define PHW_  3364      // 58*58
#define CIN_  128
#define COUT_ 256
#define NB_   32
#define KCNT  100352.0f // 32*56*56

#define XP_ELEMS (NB_*CIN_*PHW_)   // 13,778,944 bf16
#define WT_ELEMS (9*CIN_*COUT_)    // 294,912 bf16
#define WT_OFFB  (XP_ELEMS*2)      // byte offset of wT in ws
#define ST_OFFB  (WT_OFFB + WT_ELEMS*2)  // byte offset of stats (512 f32)

#define LDA_ 40   // padded LDS row length (32 + 8), 2-way-free on b128 reads

// ---------------- pad + fp32->bf16 convert: x (32,128,56,56) -> xp (32,128,58,58) ----------------
extern "C" __global__ void pad_kernel(const float* __restrict__ x, u16* __restrict__ xp)
{
    const int idx = blockIdx.x * 256 + threadIdx.x;   // exact grid, no tail
    const int wp = idx % PW_;
    const int t2 = idx / PW_;
    const int hp = t2 % PW_;
    const int nc = t2 / PW_;
    float v = 0.f;
    if (hp >= 1 && hp <= W_ && wp >= 1 && wp <= W_)
        v = x[nc * HW_ + (hp - 1) * W_ + (wp - 1)];
    __hip_bfloat16 b = __float2bfloat16(v);
    xp[idx] = *(u16*)&b;
}

// ---------------- weight transform: wgt (Cout,Cin,3,3) fp32 -> wT[tap][cin][cout] bf16 ----------------
extern "C" __global__ void wt_kernel(const float* __restrict__ wgt, u16* __restrict__ wt)
{
    const int e  = blockIdx.x * 256 + threadIdx.x;    // exact grid
    const int co = e & (COUT_ - 1);
    const int t2 = e >> 8;
    const int ci = t2 & (CIN_ - 1);
    const int tap = t2 >> 7;
    __hip_bfloat16 b = __float2bfloat16(wgt[co * 1152 + ci * 9 + tap]);
    wt[e] = *(u16*)&b;
}

// ---------------- conv (implicit GEMM, bf16 MFMA) + bias + fused channel sum/sumsq ----------------
extern "C" __global__ void __launch_bounds__(256)
conv_kernel(const u16* __restrict__ xp, const u16* __restrict__ wt,
            const float* __restrict__ bias, float* __restrict__ out,
            float* __restrict__ stats)
{
    __shared__ short As[128 * LDA_];
    __shared__ short Bs[128 * LDA_];

    const int t = threadIdx.x;
    const int mbase = blockIdx.x * 128;   // 784 M-tiles
    const int cbase = blockIdx.y * 128;   // 2 Cout-tiles

    // staging geometry: thread owns m = t&127; covers cins [a0,a0+8) and [a0+16,a0+24)
    const int sm = t & 127;
    const int a0 = (t >> 7) * 8;

    const int mg  = mbase + sm;
    const int n0  = mg / HW_;
    const int hw0 = mg % HW_;
    const int h0  = hw0 / W_;
    const int w0  = hw0 % W_;
    const int xbase = n0 * (CIN_ * PHW_) + h0 * PW_ + w0;  // elem index, cin=0,kh=0,kw=0

    f32x4 acc[4][4];
    #pragma unroll
    for (int i = 0; i < 4; ++i)
        #pragma unroll
        for (int j = 0; j < 4; ++j) acc[i][j] = (f32x4){0.f, 0.f, 0.f, 0.f};

    const int lane = t & 63;
    const int wid  = t >> 6;
    const int wr = wid >> 1, wc = wid & 1;      // 2x2 wave grid, each 64x64
    const int frow = lane & 15;
    const int koff = (lane >> 4) * 8;
    const int arow0 = (wr * 64 + frow) * LDA_ + koff;
    const int brow0 = (wc * 64 + frow) * LDA_ + koff;

    int tap = 0;
    #pragma unroll 1
    for (int kh = 0; kh < 3; ++kh) {
        #pragma unroll 1
        for (int kw = 0; kw < 3; ++kw, ++tap) {
            const int xtap = xbase + kh * PW_ + kw;
            #pragma unroll 1
            for (int cinb = 0; cinb < CIN_; cinb += 32) {
                // issue all 32 staging loads before the barrier (overlap prev MFMA)
                v8s pa0, pa1, pb0, pb1;
                const u16* ap = xp + xtap + (cinb + a0) * PHW_;
                const u16* bp = wt + (tap * CIN_ + cinb + a0) * COUT_ + cbase + sm;
                #pragma unroll
                for (int j = 0; j < 8; ++j) {
                    pa0[j] = (short)ap[j * PHW_];
                    pa1[j] = (short)ap[(16 + j) * PHW_];
                    pb0[j] = (short)bp[j * COUT_];
                    pb1[j] = (short)bp[(16 + j) * COUT_];
                }
                __syncthreads();   // prev iteration's LDS reads done
                *(v8s*)&As[sm * LDA_ + a0]      = pa0;
                *(v8s*)&As[sm * LDA_ + a0 + 16] = pa1;
                *(v8s*)&Bs[sm * LDA_ + a0]      = pb0;
                *(v8s*)&Bs[sm * LDA_ + a0 + 16] = pb1;
                __syncthreads();   // writes visible

                v8s af[4], bfr[4];
                #pragma unroll
                for (int mf = 0; mf < 4; ++mf)
                    af[mf] = *(const v8s*)&As[arow0 + mf * 16 * LDA_];
                #pragma unroll
                for (int nf = 0; nf < 4; ++nf)
                    bfr[nf] = *(const v8s*)&Bs[brow0 + nf * 16 * LDA_];
                #pragma unroll
                for (int mf = 0; mf < 4; ++mf)
                    #pragma unroll
                    for (int nf = 0; nf < 4; ++nf)
                        acc[mf][nf] = __builtin_amdgcn_mfma_f32_16x16x32_bf16(
                            af[mf], bfr[nf], acc[mf][nf], 0, 0, 0);
            }
        }
    }

    // epilogue: bias, store conv output (fp32, NCHW), fused channel sum/sumsq
    const int lgrp = lane >> 4;
    #pragma unroll
    for (int nf = 0; nf < 4; ++nf) {
        const int co = cbase + wc * 64 + nf * 16 + frow;  // C/D: col = lane&15
        const float bv = bias[co];
        float s = 0.f, q = 0.f;
        #pragma unroll
        for (int mf = 0; mf < 4; ++mf) {
            const int mloc = wr * 64 + mf * 16 + lgrp * 4; // C/D: row = (lane>>4)*4+i
            const int mg2  = mbase + mloc;                 // multiple of 4; 3136%4==0 -> no n-cross
            const int n2   = mg2 / HW_;
            const int hw2  = mg2 % HW_;
            float4 ov;
            float vx;
            vx = acc[mf][nf][0] + bv; ov.x = vx; s += vx; q += vx * vx;
            vx = acc[mf][nf][1] + bv; ov.y = vx; s += vx; q += vx * vx;
            vx = acc[mf][nf][2] + bv; ov.z = vx; s += vx; q += vx * vx;
            vx = acc[mf][nf][3] + bv; ov.w = vx; s += vx; q += vx * vx;
            *(float4*)(out + (n2 * COUT_ + co) * HW_ + hw2) = ov;
        }
        s += __shfl_xor(s, 16); s += __shfl_xor(s, 32);
        q += __shfl_xor(q, 16); q += __shfl_xor(q, 32);
        if (lgrp == 0) {
            atomicAdd(&stats[co], s);
            atomicAdd(&stats[COUT_ + co], q);
        }
    }
}

// ---------------- BN(training) + ReLU, in place on d_out ----------------
extern "C" __global__ void bn_kernel(float* __restrict__ y, const float* __restrict__ stats,
                                     const float* __restrict__ gamma, const float* __restrict__ beta)
{
    const int i4 = blockIdx.x * 256 + threadIdx.x;  // exact grid over float4s
    const int e  = i4 * 4;
    const int co = (e / HW_) & (COUT_ - 1);
    const float inv  = 1.f / KCNT;
    const float mean = stats[co] * inv;
    const float var  = stats[COUT_ + co] * inv - mean * mean;
    const float scale = gamma[co] * rsqrtf(var + 1e-5f);
    const float shift = beta[co] - mean * scale;
    float4 v = *(float4*)(y + e);
    v.x = fmaxf(fmaf(v.x, scale, shift), 0.f);
    v.y = fmaxf(fmaf(v.y, scale, shift), 0.f);
    v.z = fmaxf(fmaf(v.z, scale, shift), 0.f);
    v.w = fmaxf(fmaf(v.w, scale, shift), 0.f);
    *(float4*)(y + e) = v;
}

extern "C" void kernel_launch(void* const* d_in, const int* in_sizes, int n_in,
                              void* d_out, int out_size, void* d_ws, size_t ws_size,
                              hipStream_t stream)
{
    const float* x     = (const float*)d_in[0];
    const float* wgt   = (const float*)d_in[1];
    const float* bias  = (const float*)d_in[2];
    const float* gamma = (const float*)d_in[3];
    const float* beta  = (const float*)d_in[4];
    float* out = (float*)d_out;

    char* ws = (char*)d_ws;
    u16*   xp    = (u16*)ws;                 // 27,557,888 B
    u16*   wt    = (u16*)(ws + WT_OFFB);     //    589,824 B
    float* stats = (float*)(ws + ST_OFFB);   //      2,048 B  (total ~28.15 MB)

    hipMemsetAsync(stats, 0, 2 * COUT_ * sizeof(float), stream);

    pad_kernel<<<XP_ELEMS / 256, 256, 0, stream>>>(x, xp);            // 53824 blocks
    wt_kernel<<<WT_ELEMS / 256, 256, 0, stream>>>(wgt, wt);           // 1152 blocks
    conv_kernel<<<dim3(784, 2), 256, 0, stream>>>(xp, wt, bias, out, stats);
    bn_kernel<<<(out_size / 4) / 256, 256, 0, stream>>>(out, stats, gamma, beta); // 25088 blocks
}

// Round 2
// 263.685 us; speedup vs baseline: 1.3115x; 1.3115x over previous
//
#include <hip/hip_runtime.h>
#include <hip/hip_bf16.h>

typedef short v8s __attribute__((ext_vector_type(8)));
typedef float f32x4 __attribute__((ext_vector_type(4)));
typedef unsigned short u16;
typedef unsigned int u32;

#define HW_   3136      // 56*56
#define W_    56
#define PW_   58
#define CIN_  128
#define COUT_ 256
#define NB_   32
#define KCNT  100352.0f // 32*56*56

// xp: NHWC padded bf16 [32][58][58][128]
#define XP_ELEMS (NB_*PW_*PW_*CIN_)      // 13,778,944
#define WT_ELEMS (9*COUT_*CIN_)          // 294,912
#define WT_OFFB  (XP_ELEMS*2)
#define ST_OFFB  (WT_OFFB + WT_ELEMS*2)

#define GLOAD16(g, l) __builtin_amdgcn_global_load_lds( \
    (const __attribute__((address_space(1))) u32*)(g), \
    (__attribute__((address_space(3))) u32*)(l), 16, 0, 0)

// ---------------- pad + transpose: x (32,128,56,56) f32 -> xp (32,58,58,128) bf16 ----------------
extern "C" __global__ void __launch_bounds__(256)
pad_kernel(const float* __restrict__ x, u16* __restrict__ xp)
{
    const int b  = blockIdx.x;          // 32*58 blocks: (n, hp)
    const int n  = b / PW_;
    const int hp = b % PW_;
    u16* rowp = xp + ((n * PW_ + hp) * PW_) * CIN_;   // 58*128 elems
    const int tid = threadIdx.x;

    if (hp == 0 || hp == PW_ - 1) {
        for (int j = tid; j < PW_ * CIN_ / 8; j += 256)
            *(v8s*)&rowp[j * 8] = (v8s){0,0,0,0,0,0,0,0};
        return;
    }

    __shared__ u16 tile[CIN_ * 57];     // [c][w], stride 57
    const float* xrow = x + (n * CIN_) * HW_ + (hp - 1) * W_;
    for (int idx = tid; idx < CIN_ * W_; idx += 256) {
        const int c = idx / W_;
        const int w = idx - c * W_;
        __hip_bfloat16 bv = __float2bfloat16(xrow[c * HW_ + w]);
        tile[c * 57 + w] = *(u16*)&bv;
    }
    __syncthreads();

    if (tid < 32) {                     // wp=0 and wp=57 borders
        const int wp = (tid >> 4) * (PW_ - 1);
        const int cg = tid & 15;
        *(v8s*)&rowp[wp * CIN_ + cg * 8] = (v8s){0,0,0,0,0,0,0,0};
    }
    for (int idx = tid; idx < W_ * 16; idx += 256) {   // 896 chunks of 8 c's
        const int wp = (idx >> 4) + 1;
        const int cg = idx & 15;
        v8s v;
        #pragma unroll
        for (int j = 0; j < 8; ++j)
            v[j] = (short)tile[(cg * 8 + j) * 57 + (wp - 1)];
        *(v8s*)&rowp[wp * CIN_ + cg * 8] = v;
    }
}

// ---------------- weight transform: wgt (Cout,Cin,3,3) f32 -> wt[tap][cout][cin] bf16 ----------------
extern "C" __global__ void wt_kernel(const float* __restrict__ wgt, u16* __restrict__ wt)
{
    const int e   = blockIdx.x * 256 + threadIdx.x;  // 294912 -> 1152 blocks
    const int ci  = e & 127;
    const int t2  = e >> 7;
    const int co  = t2 & 255;
    const int tap = t2 >> 8;
    __hip_bfloat16 b = __float2bfloat16(wgt[co * 1152 + ci * 9 + tap]);
    wt[e] = *(u16*)&b;
}

// ---------------- conv: implicit GEMM, 128x128 tile, BK=64, gload_lds + XOR swizzle ----------------
extern "C" __global__ void __launch_bounds__(256)
conv_kernel(const u16* __restrict__ xp, const u16* __restrict__ wt,
            const float* __restrict__ bias, float* __restrict__ out,
            float* __restrict__ stats)
{
    __shared__ u16 As[128 * 64];
    __shared__ u16 Bs[128 * 64];

    const int t    = threadIdx.x;
    const int lane = t & 63;
    const int wid  = t >> 6;

    // XCD-bijective remap: 1568 blocks, 196 per XCD chunk; pairs (2j,2j+1) share A-tile
    const int bid     = blockIdx.x;
    const int logical = (bid & 7) * 196 + (bid >> 3);
    const int cbase   = (logical & 1) << 7;
    const int mbase   = (logical >> 1) << 7;

    // staging geometry: gload i stages 8 rows; lane -> row wid*32+i*8+(lane>>3), swizzled cin chunk
    const int srow = lane >> 3;                       // 0..7 == (LDS row & 7)
    const int scol = ((lane & 7) ^ srow) << 3;        // involutive source pre-swizzle (16B chunks)
    int xa[4], wb[4];
    #pragma unroll
    for (int i = 0; i < 4; ++i) {
        const int r   = wid * 32 + i * 8 + srow;
        const int m   = mbase + r;
        const int n0  = m / HW_;
        const int hw0 = m - n0 * HW_;
        const int h0  = hw0 / W_;
        const int w0  = hw0 - h0 * W_;
        xa[i] = ((n0 * PW_ + h0) * PW_ + w0) * CIN_ + scol;
        wb[i] = (cbase + r) * CIN_ + scol;
    }

    f32x4 acc[4][4];
    #pragma unroll
    for (int i = 0; i < 4; ++i)
        #pragma unroll
        for (int j = 0; j < 4; ++j) acc[i][j] = (f32x4){0.f, 0.f, 0.f, 0.f};

    const int wr = wid >> 1, wc = wid & 1;   // 2x2 wave grid, 64x64 each
    const int frow = lane & 15;
    const int kg   = lane >> 4;              // 0..3

    #pragma unroll 1
    for (int kh = 0; kh < 3; ++kh) {
        #pragma unroll 1
        for (int kw = 0; kw < 3; ++kw) {
            const int xoff  = (kh * PW_ + kw) * CIN_;
            const int woff2 = (kh * 3 + kw) * (COUT_ * CIN_);
            #pragma unroll 1
            for (int half = 0; half < 2; ++half) {
                const int cinb = half << 6;
                __syncthreads();   // prev LDS reads done
                #pragma unroll
                for (int i = 0; i < 4; ++i) {
                    GLOAD16(xp + xa[i] + xoff + cinb,  &As[(wid * 32 + i * 8) * 64]);
                    GLOAD16(wt + wb[i] + woff2 + cinb, &Bs[(wid * 32 + i * 8) * 64]);
                }
                __syncthreads();   // vmcnt(0) drained by compiler before barrier
                #pragma unroll
                for (int ks = 0; ks < 2; ++ks) {
                    v8s af[4], bf4[4];
                    #pragma unroll
                    for (int mf = 0; mf < 4; ++mf) {
                        const int row = wr * 64 + mf * 16 + frow;
                        const int ch  = (ks * 4 + kg) ^ (row & 7);
                        af[mf] = *(const v8s*)&As[row * 64 + ch * 8];
                    }
                    #pragma unroll
                    for (int nf = 0; nf < 4; ++nf) {
                        const int row = wc * 64 + nf * 16 + frow;
                        const int ch  = (ks * 4 + kg) ^ (row & 7);
                        bf4[nf] = *(const v8s*)&Bs[row * 64 + ch * 8];
                    }
                    #pragma unroll
                    for (int mf = 0; mf < 4; ++mf)
                        #pragma unroll
                        for (int nf = 0; nf < 4; ++nf)
                            acc[mf][nf] = __builtin_amdgcn_mfma_f32_16x16x32_bf16(
                                af[mf], bf4[nf], acc[mf][nf], 0, 0, 0);
                }
            }
        }
    }

    // epilogue: bias + store fp32 NCHW + fused channel sum/sumsq (verified R1 layout)
    const int lgrp = lane >> 4;
    #pragma unroll
    for (int nf = 0; nf < 4; ++nf) {
        const int co = cbase + wc * 64 + nf * 16 + frow;   // C/D col = lane&15
        const float bv = bias[co];
        float s = 0.f, q = 0.f;
        #pragma unroll
        for (int mf = 0; mf < 4; ++mf) {
            const int mloc = wr * 64 + mf * 16 + lgrp * 4; // C/D row = (lane>>4)*4+i
            const int mg2  = mbase + mloc;
            const int n2   = mg2 / HW_;
            const int hw2  = mg2 - n2 * HW_;
            float4 ov; float vx;
            vx = acc[mf][nf][0] + bv; ov.x = vx; s += vx; q += vx * vx;
            vx = acc[mf][nf][1] + bv; ov.y = vx; s += vx; q += vx * vx;
            vx = acc[mf][nf][2] + bv; ov.z = vx; s += vx; q += vx * vx;
            vx = acc[mf][nf][3] + bv; ov.w = vx; s += vx; q += vx * vx;
            *(float4*)(out + (n2 * COUT_ + co) * HW_ + hw2) = ov;
        }
        s += __shfl_xor(s, 16); s += __shfl_xor(s, 32);
        q += __shfl_xor(q, 16); q += __shfl_xor(q, 32);
        if (lgrp == 0) {
            atomicAdd(&stats[co], s);
            atomicAdd(&stats[COUT_ + co], q);
        }
    }
}

// ---------------- BN(training) + ReLU, in place on d_out ----------------
extern "C" __global__ void bn_kernel(float* __restrict__ y, const float* __restrict__ stats,
                                     const float* __restrict__ gamma, const float* __restrict__ beta)
{
    const int i4 = blockIdx.x * 256 + threadIdx.x;
    const int e  = i4 * 4;
    const int co = (e / HW_) & (COUT_ - 1);
    const float inv  = 1.f / KCNT;
    const float mean = stats[co] * inv;
    const float var  = stats[COUT_ + co] * inv - mean * mean;
    const float scale = gamma[co] * rsqrtf(var + 1e-5f);
    const float shift = beta[co] - mean * scale;
    float4 v = *(float4*)(y + e);
    v.x = fmaxf(fmaf(v.x, scale, shift), 0.f);
    v.y = fmaxf(fmaf(v.y, scale, shift), 0.f);
    v.z = fmaxf(fmaf(v.z, scale, shift), 0.f);
    v.w = fmaxf(fmaf(v.w, scale, shift), 0.f);
    *(float4*)(y + e) = v;
}

extern "C" void kernel_launch(void* const* d_in, const int* in_sizes, int n_in,
                              void* d_out, int out_size, void* d_ws, size_t ws_size,
                              hipStream_t stream)
{
    const float* x     = (const float*)d_in[0];
    const float* wgt   = (const float*)d_in[1];
    const float* bias  = (const float*)d_in[2];
    const float* gamma = (const float*)d_in[3];
    const float* beta  = (const float*)d_in[4];
    float* out = (float*)d_out;

    char* ws = (char*)d_ws;
    u16*   xp    = (u16*)ws;
    u16*   wt    = (u16*)(ws + WT_OFFB);
    float* stats = (float*)(ws + ST_OFFB);

    hipMemsetAsync(stats, 0, 2 * COUT_ * sizeof(float), stream);

    pad_kernel<<<NB_ * PW_, 256, 0, stream>>>(x, xp);                 // 1856 blocks
    wt_kernel<<<WT_ELEMS / 256, 256, 0, stream>>>(wgt, wt);           // 1152 blocks
    conv_kernel<<<1568, 256, 0, stream>>>(xp, wt, bias, out, stats);
    bn_kernel<<<(out_size / 4) / 256, 256, 0, stream>>>(out, stats, gamma, beta);
}